// Round 2
// baseline (1445.439 us; speedup 1.0000x reference)
//
#include <hip/hip_runtime.h>

// Problem constants (z: [32,256,32,32] fp32, codebook: [1024,256] fp32)
constexpr int D_ = 256;    // latent dim
constexpr int K_ = 1024;   // codebook size
constexpr int P_ = 1024;   // H*W
constexpr int N_ = 32768;  // B*H*W rows

// d_out layout (float32): z_q [8388608] ++ idx-as-float [32768] ++ loss [1]
constexpr int IDX_OFF  = 8388608;
constexpr int LOSS_OFF = 8421376;

// ---------------------------------------------------------------------------
// pass0: cnorm[k] = ||codebook[k]||^2 -> parked in out[0..1023] (z_q region,
// overwritten later by gather). Also zero the loss slot.
// fp64 accum then fp32 round: within ~1e-11 of numpy's fp32 pairwise sum,
// vs a 4.6e-6 cross-k spread -> rounding-pattern-equivalent.
__global__ __launch_bounds__(64) void vq_prep(const float* __restrict__ cb,
                                              float* __restrict__ out) {
  const int k = blockIdx.x;
  const int lane = threadIdx.x;
  const float* row = cb + (size_t)k * D_;
  double s = 0.0;
  #pragma unroll
  for (int i = 0; i < D_ / 64; ++i) {
    double v = (double)row[lane + i * 64];
    s = fma(v, v, s);
  }
  #pragma unroll
  for (int off = 32; off; off >>= 1) s += __shfl_down(s, off, 64);
  if (lane == 0) out[k] = (float)s;
  if (k == 0 && lane == 0) out[LOSS_OFF] = 0.0f;
}

// ---------------------------------------------------------------------------
// pass1: replicate the reference's fp32 score EXACTLY at the combine step:
//   s_k = fl32( fl32(zn + cn_k) - 2*dot_k )        (2*dot exact in binary fp)
// and argmin with GLOBAL first-index tie-break (fp32 quantization at
// ulp(~256)~3e-5 makes exact ties common; numpy argmin takes first).
// zn only needs to be a nearby fp32 value (ulp-shift equivariance of the
// uniform fp32 grid around 256), so any sane summation order works.
// Block = 256 threads = 4 waves; lane = row (64 rows/block, same batch b).
// Each wave owns 64 k's per chunk (uniform codebook addr -> s_load), 4 chunks.
__global__ __launch_bounds__(256) void vq_argmin(const float* __restrict__ z,
                                                 const float* __restrict__ cb,
                                                 const float* __restrict__ cnorm,
                                                 float* __restrict__ idxf) {
  const int tid = threadIdx.x;
  const int lane = tid & 63;
  const int w = __builtin_amdgcn_readfirstlane(tid >> 6);
  const int n0 = blockIdx.x * 64;
  const int b = n0 >> 10;
  const int p0 = n0 & (P_ - 1);
  const float* zrow = z + (size_t)b * (D_ * P_) + p0 + lane;  // + c*P_

  // per-row ||z||^2 in fp32 (8 partials + tree combine: few-ulp accurate)
  float zsq[8];
  #pragma unroll
  for (int i = 0; i < 8; ++i) zsq[i] = 0.0f;
  for (int oct = 0; oct < 32; ++oct) {
    #pragma unroll
    for (int i = 0; i < 8; ++i) {
      float v = zrow[(size_t)(oct * 8 + i) * P_];
      zsq[i] = fmaf(v, v, zsq[i]);
    }
  }
  const float zn = ((zsq[0] + zsq[1]) + (zsq[2] + zsq[3])) +
                   ((zsq[4] + zsq[5]) + (zsq[6] + zsq[7]));

  float m1 = 1e30f;
  int i1 = 0x7fffffff;

  for (int kc = 0; kc < 4; ++kc) {
    const int kbase = kc * 256 + w * 64;
    float acc[64];
    #pragma unroll
    for (int j = 0; j < 64; ++j) acc[j] = 0.0f;

    // software-pipelined z loads (8 c's per step, 32 steps over D=256)
    float zr[8], znx[8];
    #pragma unroll
    for (int i = 0; i < 8; ++i) zr[i] = zrow[(size_t)i * P_];

    for (int oct = 0; oct < 32; ++oct) {
      if (oct < 31) {
        #pragma unroll
        for (int i = 0; i < 8; ++i) znx[i] = zrow[(size_t)((oct + 1) * 8 + i) * P_];
      }
      #pragma unroll
      for (int j = 0; j < 64; ++j) {
        const float* cbp = cb + (size_t)(kbase + j) * D_ + oct * 8;  // uniform -> s_load
        #pragma unroll
        for (int i = 0; i < 8; ++i) acc[j] = fmaf(zr[i], cbp[i], acc[j]);
      }
      #pragma unroll
      for (int i = 0; i < 8; ++i) zr[i] = znx[i];
    }

    // k ascends within this wave's sequence -> strict < keeps first index
    #pragma unroll
    for (int j = 0; j < 64; ++j) {
      float A = zn + cnorm[kbase + j];   // fl32 (matches reference order)
      float s = A - 2.0f * acc[j];       // fl32 / exact-equivalent fma
      if (s < m1) { m1 = s; i1 = kbase + j; }
    }
  }

  // merge the 4 waves' (m1, i1) per row with value-then-index tie-break
  __shared__ float sm1[4][64];
  __shared__ int   si1[4][64];
  sm1[w][lane] = m1; si1[w][lane] = i1;
  __syncthreads();
  if (tid < 64) {
    float M1 = sm1[0][lane];
    int   I1 = si1[0][lane];
    #pragma unroll
    for (int ww = 1; ww < 4; ++ww) {
      float a1 = sm1[ww][lane];
      int   ai = si1[ww][lane];
      if (a1 < M1 || (a1 == M1 && ai < I1)) { M1 = a1; I1 = ai; }
    }
    idxf[n0 + lane] = (float)I1;
  }
}

// ---------------------------------------------------------------------------
// pass2: gather z_q = codebook[idx] into NCHW + loss. STE write replicates
// the reference's fp32 rounding exactly: out = z + (v - z).
__global__ __launch_bounds__(256) void vq_gather(const float* __restrict__ z,
                                                 const float* __restrict__ cb,
                                                 const float* __restrict__ idxf,
                                                 float* __restrict__ out,
                                                 float* __restrict__ loss) {
  const int tid = threadIdx.x;
  const int lane = tid & 63;
  const int w = tid >> 6;
  const int n0 = blockIdx.x * 64;
  const int b = n0 >> 10;
  const int p0 = n0 & (P_ - 1);
  const int p = p0 + lane;

  const int idx = (int)(idxf[n0 + lane] + 0.5f);
  const float* crow = cb + (size_t)idx * D_;
  const size_t base = (size_t)b * (D_ * P_) + p;

  float acc = 0.0f;
  #pragma unroll 4
  for (int ci = 0; ci < 64; ++ci) {
    const int c = w + ci * 4;
    const float v = crow[c];          // gather (1 MB table, L1/L2 resident)
    const size_t a = base + (size_t)c * P_;
    const float zv = z[a];
    const float d = v - zv;           // fl32
    out[a] = zv + d;                  // fl32 STE: z + sg(z_q - z), bit-exact
    acc = fmaf(d, d, acc);
  }
  #pragma unroll
  for (int off = 32; off; off >>= 1) acc += __shfl_down(acc, off, 64);
  __shared__ float wsum[4];
  if (lane == 0) wsum[w] = acc;
  __syncthreads();
  if (tid == 0) {
    float s = wsum[0] + wsum[1] + wsum[2] + wsum[3];
    atomicAdd(loss, s * (1.25f / 8388608.0f));  // (1+BETA)/(B*H*W*C)
  }
}

// ---------------------------------------------------------------------------
extern "C" void kernel_launch(void* const* d_in, const int* in_sizes, int n_in,
                              void* d_out, int out_size, void* d_ws, size_t ws_size,
                              hipStream_t stream) {
  const float* z  = (const float*)d_in[0];
  const float* cb = (const float*)d_in[1];
  float* out = (float*)d_out;

  vq_prep<<<K_, 64, 0, stream>>>(cb, out);
  vq_argmin<<<N_ / 64, 256, 0, stream>>>(z, cb, /*cnorm=*/out, out + IDX_OFF);
  vq_gather<<<N_ / 64, 256, 0, stream>>>(z, cb, out + IDX_OFF, out, out + LOSS_OFF);
}

// Round 3
// 395.047 us; speedup vs baseline: 3.6589x; 3.6589x over previous
//
#include <hip/hip_runtime.h>

// Problem constants (z: [32,256,32,32] fp32, codebook: [1024,256] fp32)
constexpr int D_ = 256;    // latent dim
constexpr int K_ = 1024;   // codebook size
constexpr int P_ = 1024;   // H*W
constexpr int N_ = 32768;  // B*H*W rows

// d_out layout (float32): z_q [8388608] ++ idx-as-float [32768] ++ loss [1]
constexpr int IDX_OFF  = 8388608;
constexpr int LOSS_OFF = 8421376;

// d_ws layout (float32): cnorm [1024] ++ zn [32768]
constexpr int WS_CNORM = 0;
constexpr int WS_ZN    = 1024;

// ---------------------------------------------------------------------------
// prep: blocks 0..511 -> zn[row] = ||z_row||^2 (EXACT same fma order + tree
// combine as the previously-passing kernel -> bit-identical zn).
// blocks 512..1535 -> cnorm[k] via fp64 (same as passing version).
__global__ __launch_bounds__(64) void vq_norms(const float* __restrict__ z,
                                               const float* __restrict__ cb,
                                               float* __restrict__ cnorm,
                                               float* __restrict__ zn,
                                               float* __restrict__ loss) {
  const int blk = blockIdx.x;
  const int lane = threadIdx.x;
  if (blk < 512) {
    const int n0 = blk * 64;
    const int b = n0 >> 10, p0 = n0 & (P_ - 1);
    const float* zp = z + (size_t)b * (D_ * P_) + p0 + lane;
    float a8[8];
    #pragma unroll
    for (int i = 0; i < 8; ++i) a8[i] = 0.0f;
    for (int oct = 0; oct < 32; ++oct) {
      #pragma unroll
      for (int i = 0; i < 8; ++i) {
        float v = zp[(size_t)(oct * 8 + i) * P_];
        a8[i] = fmaf(v, v, a8[i]);
      }
    }
    zn[n0 + lane] = ((a8[0] + a8[1]) + (a8[2] + a8[3])) +
                    ((a8[4] + a8[5]) + (a8[6] + a8[7]));
    if (blk == 0 && lane == 0) *loss = 0.0f;
  } else {
    const int k = blk - 512;
    const float* row = cb + (size_t)k * D_;
    double s = 0.0;
    #pragma unroll
    for (int i = 0; i < 4; ++i) {
      double v = (double)row[lane + i * 64];
      s = fma(v, v, s);
    }
    #pragma unroll
    for (int off = 32; off; off >>= 1) s += __shfl_down(s, off, 64);
    if (lane == 0) cnorm[k] = (float)s;
  }
}

// ---------------------------------------------------------------------------
// main: register-tiled LDS GEMM + fused argmin.
// Block 256 thr = 16 row-groups (rg) x 16 k-groups (kgt). Per thread:
// 4 rows x 16 k = 64 fp32 accumulators (register tile). K-tiles of 256
// (4 iters), d-tiles of 32 (8 iters) with register prefetch of the next
// global tile. Score s = fl(zn+cn) - 2*dot, fma order over d identical to
// the passing round -> bit-identical idx. First-index tie-break globally.
constexpr int DT = 32;            // d-tile
constexpr int BS_STRIDE = 516;    // 32*16 + 4 pad floats per k-group slab

__global__ __launch_bounds__(256, 2) void vq_main(const float* __restrict__ z,
                                                  const float* __restrict__ cb,
                                                  const float* __restrict__ cnorm,
                                                  const float* __restrict__ zn,
                                                  float* __restrict__ idxf) {
  const int t = threadIdx.x;
  const int n0 = blockIdx.x * 64;
  const int b = n0 >> 10, p0 = n0 & (P_ - 1);
  const int rg = t >> 4;    // 0..15 row-group
  const int kgt = t & 15;   // 0..15 k-group

  __shared__ alignas(16) float As[DT * 64];          // [d][row] (2-way, free)
  __shared__ alignas(16) float Bs[16 * BS_STRIDE];   // slab[kgt][d*16+kj]

  // A staging: thread loads rowA = t&63 at d = dA0..dA0+7 (coalesced lanes)
  const int rowA = t & 63;
  const int dA0 = (t >> 6) * 8;
  const float* zb = z + (size_t)b * (D_ * P_) + p0 + rowA;

  // B staging: 8 consecutive lanes read one 128B row chunk (float4 each)
  const int jB = t & 7;     // which float4 of the 32-d chunk
  const int kB = t >> 3;    // 0..31; k_local = kB + 32*i
  const float4* cb4 = (const float4*)cb;

  float znr[4];
  #pragma unroll
  for (int rr = 0; rr < 4; ++rr) znr[rr] = zn[n0 + rg * 4 + rr];

  float m1[4]; int i1[4];
  #pragma unroll
  for (int rr = 0; rr < 4; ++rr) { m1[rr] = 1e30f; i1[rr] = 0x7fffffff; }

  for (int kt = 0; kt < 4; ++kt) {
    const int k0 = kt * 256;
    float acc[4][16];
    #pragma unroll
    for (int rr = 0; rr < 4; ++rr)
      #pragma unroll
      for (int j = 0; j < 16; ++j) acc[rr][j] = 0.0f;

    // prefetch d-tile 0 into registers
    float Ar[8]; float4 Br[8];
    #pragma unroll
    for (int i = 0; i < 8; ++i) Ar[i] = zb[(size_t)(dA0 + i) * P_];
    #pragma unroll
    for (int i = 0; i < 8; ++i)
      Br[i] = cb4[(size_t)(k0 + kB + 32 * i) * 64 + jB];

    for (int dt = 0; dt < 8; ++dt) {
      __syncthreads();   // previous tile's compute done before overwrite
      #pragma unroll
      for (int i = 0; i < 8; ++i) As[(dA0 + i) * 64 + rowA] = Ar[i];
      #pragma unroll
      for (int i = 0; i < 8; ++i) {
        const int kl = kB + 32 * i;
        float* s = &Bs[(kl >> 4) * BS_STRIDE + (kl & 15)];
        s[(jB * 4 + 0) * 16] = Br[i].x;
        s[(jB * 4 + 1) * 16] = Br[i].y;
        s[(jB * 4 + 2) * 16] = Br[i].z;
        s[(jB * 4 + 3) * 16] = Br[i].w;
      }
      __syncthreads();
      if (dt < 7) {      // prefetch next tile (hidden under compute below)
        const int d0 = (dt + 1) * DT;
        #pragma unroll
        for (int i = 0; i < 8; ++i) Ar[i] = zb[(size_t)(d0 + dA0 + i) * P_];
        #pragma unroll
        for (int i = 0; i < 8; ++i)
          Br[i] = cb4[(size_t)(k0 + kB + 32 * i) * 64 + (d0 >> 2) + jB];
      }
      #pragma unroll 8
      for (int d = 0; d < DT; ++d) {
        const float4 a  = *(const float4*)&As[d * 64 + rg * 4];
        const float4 b0 = *(const float4*)&Bs[kgt * BS_STRIDE + d * 16 + 0];
        const float4 b1 = *(const float4*)&Bs[kgt * BS_STRIDE + d * 16 + 4];
        const float4 b2 = *(const float4*)&Bs[kgt * BS_STRIDE + d * 16 + 8];
        const float4 b3 = *(const float4*)&Bs[kgt * BS_STRIDE + d * 16 + 12];
        const float av[4]  = {a.x, a.y, a.z, a.w};
        const float bv[16] = {b0.x, b0.y, b0.z, b0.w, b1.x, b1.y, b1.z, b1.w,
                              b2.x, b2.y, b2.z, b2.w, b3.x, b3.y, b3.z, b3.w};
        #pragma unroll
        for (int rr = 0; rr < 4; ++rr)
          #pragma unroll
          for (int j = 0; j < 16; ++j)
            acc[rr][j] = fmaf(av[rr], bv[j], acc[rr][j]);
      }
    }

    // epilogue for this k-tile: s = fl(zn+cn) - 2*dot, strict < (k ascends)
    float cn[16];
    #pragma unroll
    for (int j = 0; j < 16; ++j) cn[j] = cnorm[k0 + kgt * 16 + j];
    #pragma unroll
    for (int rr = 0; rr < 4; ++rr)
      #pragma unroll
      for (int j = 0; j < 16; ++j) {
        const float s = fmaf(-2.0f, acc[rr][j], znr[rr] + cn[j]);
        if (s < m1[rr]) { m1[rr] = s; i1[rr] = k0 + kgt * 16 + j; }
      }
  }

  // cross-kgt merge (16 lanes per row-group, within-wave) with
  // value-then-first-index tie-break
  #pragma unroll
  for (int rr = 0; rr < 4; ++rr) {
    float m = m1[rr]; int idx = i1[rr];
    #pragma unroll
    for (int off = 1; off < 16; off <<= 1) {
      const float om = __shfl_xor(m, off, 64);
      const int   oi = __shfl_xor(idx, off, 64);
      if (om < m || (om == m && oi < idx)) { m = om; idx = oi; }
    }
    if (kgt == 0) idxf[n0 + rg * 4 + rr] = (float)idx;
  }
}

// ---------------------------------------------------------------------------
// gather: z_q = codebook[idx] into NCHW + loss. STE write replicates the
// reference's fp32 rounding exactly: out = z + (v - z).
__global__ __launch_bounds__(256) void vq_gather(const float* __restrict__ z,
                                                 const float* __restrict__ cb,
                                                 const float* __restrict__ idxf,
                                                 float* __restrict__ out,
                                                 float* __restrict__ loss) {
  const int tid = threadIdx.x;
  const int lane = tid & 63;
  const int w = tid >> 6;
  const int n0 = blockIdx.x * 64;
  const int b = n0 >> 10;
  const int p0 = n0 & (P_ - 1);
  const int p = p0 + lane;

  const int idx = (int)(idxf[n0 + lane] + 0.5f);
  const float* crow = cb + (size_t)idx * D_;
  const size_t base = (size_t)b * (D_ * P_) + p;

  float acc = 0.0f;
  #pragma unroll 4
  for (int ci = 0; ci < 64; ++ci) {
    const int c = w + ci * 4;
    const float v = crow[c];          // gather (1 MB table, L1/L2 resident)
    const size_t a = base + (size_t)c * P_;
    const float zv = z[a];
    const float d = v - zv;           // fl32
    out[a] = zv + d;                  // fl32 STE: z + sg(z_q - z), bit-exact
    acc = fmaf(d, d, acc);
  }
  #pragma unroll
  for (int off = 32; off; off >>= 1) acc += __shfl_down(acc, off, 64);
  __shared__ float wsum[4];
  if (lane == 0) wsum[w] = acc;
  __syncthreads();
  if (tid == 0) {
    float s = wsum[0] + wsum[1] + wsum[2] + wsum[3];
    atomicAdd(loss, s * (1.25f / 8388608.0f));  // (1+BETA)/(B*H*W*C)
  }
}

// ---------------------------------------------------------------------------
extern "C" void kernel_launch(void* const* d_in, const int* in_sizes, int n_in,
                              void* d_out, int out_size, void* d_ws, size_t ws_size,
                              hipStream_t stream) {
  const float* z  = (const float*)d_in[0];
  const float* cb = (const float*)d_in[1];
  float* out = (float*)d_out;
  float* ws  = (float*)d_ws;
  float* cnorm = ws + WS_CNORM;
  float* zn    = ws + WS_ZN;

  vq_norms<<<1536, 64, 0, stream>>>(z, cb, cnorm, zn, out + LOSS_OFF);
  vq_main<<<N_ / 64, 256, 0, stream>>>(z, cb, cnorm, zn, out + IDX_OFF);
  vq_gather<<<N_ / 64, 256, 0, stream>>>(z, cb, out + IDX_OFF, out, out + LOSS_OFF);
}